// Round 2
// baseline (3807.710 us; speedup 1.0000x reference)
//
#include <hip/hip_runtime.h>
#include <math.h>

#define BATCH 64
#define MM 100     // predictions per batch
#define NN 100     // targets per batch
#define NCOL 100   // square Hungarian size: max(M, K) == 100 always

// One wave (64 lanes) per batch. Lane owns columns {tid, tid+64} and rows
// {tid, tid+64} (1-based indices 1..100; column 0 is the sentinel).
// All Hungarian state except the float cost matrix lives in registers;
// cross-lane traffic is shuffles only. Double precision mirrors the numpy
// reference bit-exactly (float32 costs upcast to f64, f64 potentials).

__global__ __launch_bounds__(64) void hungarian_loss_kernel(
        const float* __restrict__ pred, const float* __restrict__ target,
        double* __restrict__ ws) {
    const int b = blockIdx.x;
    const int tid = threadIdx.x;
    const float* P = pred + b * MM * 3;
    const float* T = target + b * NN * 3;

    __shared__ float px[MM], py[MM], pc[MM];
    __shared__ float tvx[NN], tvy[NN], tvc[NN];
    __shared__ float cost[MM * NCOL];   // 40 KB, row-major [pred_row][col]

    const int tA = tid, tB = tid + 64;

    // ---- load pred into LDS ----
    if (tA < MM) { px[tA] = P[3*tA]; py[tA] = P[3*tA+1]; pc[tA] = P[3*tA+2]; }
    if (tB < MM) { px[tB] = P[3*tB]; py[tB] = P[3*tB+1]; pc[tB] = P[3*tB+2]; }

    // ---- load targets, compact valid (conf > 0.5) preserving order ----
    float cxA=0.f, cyA=0.f, ccA=0.f, cxB=0.f, cyB=0.f, ccB=0.f;
    bool vA_=false, vB_=false;
    if (tA < NN) { cxA=T[3*tA]; cyA=T[3*tA+1]; ccA=T[3*tA+2]; vA_ = ccA > 0.5f; }
    if (tB < NN) { cxB=T[3*tB]; cyB=T[3*tB+1]; ccB=T[3*tB+2]; vB_ = ccB > 0.5f; }
    unsigned long long mA = __ballot(vA_);
    unsigned long long mB = __ballot(vB_);
    int nA = __popcll(mA);
    int K  = nA + __popcll(mB);
    unsigned long long below = (1ull << tid) - 1ull;
    if (vA_) { int q = __popcll(mA & below);      tvx[q]=cxA; tvy[q]=cyA; tvc[q]=ccA; }
    if (vB_) { int q = nA + __popcll(mB & below); tvx[q]=cxB; tvy[q]=cyB; tvc[q]=ccB; }

    if (K == 0) { if (tid == 0) ws[b] = 0.0; return; }

    __syncthreads();

    // ---- cost matrix, float32 pipeline identical to np.linalg.norm ----
    float txA=0.f, tyA=0.f, txB=0.f, tyB=0.f;
    if (tid < K)      { txA = tvx[tid];    tyA = tvy[tid];    }
    if (tid + 64 < K) { txB = tvx[tid+64]; tyB = tvy[tid+64]; }
    for (int i = 0; i < MM; ++i) {
        float bx = px[i], by = py[i];
        if (tid < K) {
            float dx = __fsub_rn(bx, txA), dy = __fsub_rn(by, tyA);
            float s  = __fadd_rn(__fmul_rn(dx,dx), __fmul_rn(dy,dy));
            cost[i*NCOL + tid] = __fsqrt_rn(s);
        }
        if (tid + 64 < K) {
            float dx = __fsub_rn(bx, txB), dy = __fsub_rn(by, tyB);
            float s  = __fadd_rn(__fmul_rn(dx,dx), __fmul_rn(dy,dy));
            cost[i*NCOL + tid + 64] = __fsqrt_rn(s);
        }
    }
    __syncthreads();

    // ---- Hungarian (e-maxx / JV potentials), f64, wave-parallel columns ----
    const double INF = __builtin_inf();
    const int jA = tid;            // column 0..63 (0 = sentinel)
    const int jB = tid + 64;       // column 64..127; valid if <= 100
    const bool validB = (jB <= NCOL);

    double uA = 0.0, uB = 0.0;     // row potentials (rows tid, tid+64)
    double vvA = 0.0, vvB = 0.0;   // column potentials
    int pA = 0, pB = 0;            // p[col] = matched row (0 = free)

    for (int i = 1; i <= NCOL; ++i) {
        double minvA = INF, minvB = INF;
        int wayA = 0, wayB = 0;
        bool usedA = (tid == 0);             // column 0 used from start
        bool usedB = false;
        bool ruA = (i < 64) && (tid == i);   // row i in the used-row set
        bool ruB = (tid == i - 64);
        if (tid == 0) pA = i;                // p[0] = i
        int i0 = i;
        int j0 = 0;
        int jfree = -1;

        for (int iter = 0; iter <= NCOL; ++iter) {
            double ua = __shfl(uA, i0 & 63, 64);
            double ub = __shfl(uB, i0 & 63, 64);
            double u_i0 = (i0 < 64) ? ua : ub;

            double candA = INF, candB = INF;
            if (jA >= 1 && !usedA) {
                double c = (jA <= K) ? (double)cost[(i0-1)*NCOL + (jA-1)] : 0.0;
                double cur = c - u_i0 - vvA;
                if (cur < minvA) { minvA = cur; wayA = j0; }
                candA = minvA;
            }
            if (validB && !usedB) {
                double c = (jB <= K) ? (double)cost[(i0-1)*NCOL + (jB-1)] : 0.0;
                double cur = c - u_i0 - vvB;
                if (cur < minvB) { minvB = cur; wayB = j0; }
                candB = minvB;
            }
            // argmin with numpy tie-break (smallest column index)
            double val = candA; int idx = jA;
            if (candB < val) { val = candB; idx = jB; }
            for (int m = 1; m < 64; m <<= 1) {
                double oval = __shfl_xor(val, m, 64);
                int    oidx = __shfl_xor(idx, m, 64);
                if (oval < val || (oval == val && oidx < idx)) { val = oval; idx = oidx; }
            }
            double delta = val;
            int j1 = idx;

            // potential / minv updates (j1 still counts as unused here)
            if (ruA) uA += delta;
            if (ruB) uB += delta;
            if (usedA) vvA -= delta; else if (jA >= 1) minvA -= delta;
            if (usedB) vvB -= delta; else if (validB)  minvB -= delta;

            int pa = __shfl(pA, j1 & 63, 64);
            int pb = __shfl(pB, j1 & 63, 64);
            int pj1 = (j1 < 64) ? pa : pb;
            if (pj1 == 0) { jfree = j1; break; }

            if (jA == j1) usedA = true;
            if (jB == j1) usedB = true;
            ruA = ruA || (pj1 < 64 && tid == pj1);
            ruB = ruB || (pj1 >= 64 && tid == pj1 - 64);
            j0 = j1;
            i0 = pj1;
        }

        // ---- augment along way[] (all via shuffles) ----
        int jc = jfree;
        for (int iter = 0; iter <= NCOL && jc > 0; ++iter) {
            int wa_ = __shfl(wayA, jc & 63, 64);
            int wb_ = __shfl(wayB, jc & 63, 64);
            int w = (jc < 64) ? wa_ : wb_;
            int pa = __shfl(pA, w & 63, 64);
            int pb = __shfl(pB, w & 63, 64);
            int pw = (w < 64) ? pa : pb;
            if (jA == jc) pA = pw;
            if (jB == jc) pB = pw;
            jc = w;
        }
    }

    // ---- loss: real columns 1..K are matched to rows p[j] ----
    double se = 0.0, bce = 0.0;
    if (jA >= 1 && jA <= K) {
        int r = pA - 1;
        float dx = __fsub_rn(px[r], tvx[jA-1]);
        float dy = __fsub_rn(py[r], tvy[jA-1]);
        se = (double)dx*(double)dx + (double)dy*(double)dy;
        double pcv = (double)pc[r];
        pcv = fmin(fmax(pcv, 1e-12), 1.0 - 1e-12);
        double tc = (double)tvc[jA-1];
        bce = -(tc * log(pcv) + (1.0 - tc) * log1p(-pcv));
    }
    if (validB && jB <= K) {
        int r = pB - 1;
        float dx = __fsub_rn(px[r], tvx[jB-1]);
        float dy = __fsub_rn(py[r], tvy[jB-1]);
        se += (double)dx*(double)dx + (double)dy*(double)dy;
        double pcv = (double)pc[r];
        pcv = fmin(fmax(pcv, 1e-12), 1.0 - 1e-12);
        double tc = (double)tvc[jB-1];
        bce += -(tc * log(pcv) + (1.0 - tc) * log1p(-pcv));
    }
    for (int m = 1; m < 64; m <<= 1) {
        se  += __shfl_xor(se,  m, 64);
        bce += __shfl_xor(bce, m, 64);
    }
    if (tid == 0) ws[b] = se / (2.0 * (double)K) + bce / (double)K;
}

__global__ __launch_bounds__(64) void final_reduce(const double* __restrict__ ws,
                                                   float* __restrict__ out) {
    double v = ws[threadIdx.x];   // BATCH == 64 == one wave
    for (int m = 1; m < 64; m <<= 1) v += __shfl_xor(v, m, 64);
    if (threadIdx.x == 0) out[0] = (float)(v / (double)BATCH);
}

extern "C" void kernel_launch(void* const* d_in, const int* in_sizes, int n_in,
                              void* d_out, int out_size, void* d_ws, size_t ws_size,
                              hipStream_t stream) {
    const float* pred   = (const float*)d_in[0];
    const float* target = (const float*)d_in[1];
    double* ws = (double*)d_ws;
    float* out = (float*)d_out;
    hungarian_loss_kernel<<<dim3(BATCH), dim3(64), 0, stream>>>(pred, target, ws);
    final_reduce<<<dim3(1), dim3(64), 0, stream>>>(ws, out);
}

// Round 3
// 78.117 us; speedup vs baseline: 48.7439x; 48.7439x over previous
//
#include <hip/hip_runtime.h>
#include <math.h>

#define BATCH 64
#define MM 100     // predictions per batch (columns in the transposed problem)
#define NN 100     // targets per batch

// ---------- fast wave-uniform primitives (VALU, not LDS pipe) ----------

__device__ __forceinline__ int readlane_i(int v, int lane) {
    return __builtin_amdgcn_readlane(v, lane);
}
__device__ __forceinline__ double readlane_d(double x, int lane) {
    union { double d; int i[2]; } u; u.d = x;
    union { int i[2]; double d; } r;
    r.i[0] = __builtin_amdgcn_readlane(u.i[0], lane);
    r.i[1] = __builtin_amdgcn_readlane(u.i[1], lane);
    return r.d;
}

template<int CTRL>
__device__ __forceinline__ double dpp_min_f64(double x) {
    union { double d; int i[2]; } u, p;
    u.d = x;
    // old = src, bound_ctrl=false: lanes with invalid source keep own value
    p.i[0] = __builtin_amdgcn_update_dpp(u.i[0], u.i[0], CTRL, 0xF, 0xF, false);
    p.i[1] = __builtin_amdgcn_update_dpp(u.i[1], u.i[1], CTRL, 0xF, 0xF, false);
    return fmin(u.d, p.d);
}

// full-wave64 min; returns the min broadcast (via lane 63) to all lanes
__device__ __forceinline__ double wave_min_f64(double x) {
    x = dpp_min_f64<0xB1>(x);    // quad_perm [1,0,3,2]  (xor 1)
    x = dpp_min_f64<0x4E>(x);    // quad_perm [2,3,0,1]  (xor 2)
    x = dpp_min_f64<0x141>(x);   // row_half_mirror      (min over 8)
    x = dpp_min_f64<0x140>(x);   // row_mirror           (min over 16)
    x = dpp_min_f64<0x142>(x);   // row_bcast15          (min over 32 @ lanes 16-31/48-63)
    x = dpp_min_f64<0x143>(x);   // row_bcast31          (min over 64 @ lanes 48-63)
    return readlane_d(x, 63);
}

// One wave per batch. Transposed rectangular Hungarian: "rows" = K valid
// targets (1..K), "columns" = 100 preds (1..100) + sentinel col 0.
// Lane owns columns {tid, tid+64} and rows {tid, tid+64}; all state in
// registers; uniform broadcasts via v_readlane; argmin via DPP f64 min.

__global__ __launch_bounds__(64) void hungarian_loss_kernel(
        const float* __restrict__ pred, const float* __restrict__ target,
        double* __restrict__ ws) {
    const int b = blockIdx.x;
    const int tid = threadIdx.x;
    const float* P = pred + b * MM * 3;
    const float* T = target + b * NN * 3;

    __shared__ float px[MM], py[MM], pc[MM];
    __shared__ float tvx[NN], tvy[NN], tvc[NN];
    __shared__ float Tc[NN * MM];   // 40 KB, [target c][pred r]

    const int tA = tid, tB = tid + 64;

    // ---- load pred (registers + LDS copy for the loss epilogue) ----
    float pxA=0.f, pyA=0.f, pxB=0.f, pyB=0.f;
    if (tA < MM) { pxA = P[3*tA]; pyA = P[3*tA+1]; px[tA]=pxA; py[tA]=pyA; pc[tA]=P[3*tA+2]; }
    if (tB < MM) { pxB = P[3*tB]; pyB = P[3*tB+1]; px[tB]=pxB; py[tB]=pyB; pc[tB]=P[3*tB+2]; }

    // ---- load targets, compact valid (conf > 0.5) preserving order ----
    float cxA=0.f, cyA=0.f, ccA=0.f, cxB=0.f, cyB=0.f, ccB=0.f;
    bool vA_=false, vB_=false;
    if (tA < NN) { cxA=T[3*tA]; cyA=T[3*tA+1]; ccA=T[3*tA+2]; vA_ = ccA > 0.5f; }
    if (tB < NN) { cxB=T[3*tB]; cyB=T[3*tB+1]; ccB=T[3*tB+2]; vB_ = ccB > 0.5f; }
    unsigned long long mA = __ballot(vA_);
    unsigned long long mB = __ballot(vB_);
    int nA = __popcll(mA);
    int K  = nA + __popcll(mB);
    unsigned long long below = (1ull << tid) - 1ull;
    if (vA_) { int q = __popcll(mA & below);      tvx[q]=cxA; tvy[q]=cyA; tvc[q]=ccA; }
    if (vB_) { int q = nA + __popcll(mB & below); tvx[q]=cxB; tvy[q]=cyB; tvc[q]=ccB; }

    if (K == 0) { if (tid == 0) ws[b] = 0.0; return; }

    __syncthreads();

    // ---- transposed cost matrix, f32 pipeline identical to np.linalg.norm ----
    for (int c = 0; c < K; ++c) {
        float tx = tvx[c], ty = tvy[c];
        {
            float dx = __fsub_rn(pxA, tx), dy = __fsub_rn(pyA, ty);
            float s  = __fadd_rn(__fmul_rn(dx,dx), __fmul_rn(dy,dy));
            Tc[c*MM + tA] = __fsqrt_rn(s);
        }
        if (tB < MM) {
            float dx = __fsub_rn(pxB, tx), dy = __fsub_rn(pyB, ty);
            float s  = __fadd_rn(__fmul_rn(dx,dx), __fmul_rn(dy,dy));
            Tc[c*MM + tB] = __fsqrt_rn(s);
        }
    }
    __syncthreads();

    // ---- rectangular JV Hungarian: K phases over 100 pred-columns ----
    const double INF = __builtin_inf();
    const int jA = tid;            // column 0..63 (0 = sentinel)
    const int jB = tid + 64;       // column 64..127; valid if <= 100
    const bool validB = (jB <= MM);

    double uA = 0.0, uB = 0.0;     // row potentials (rows tid, tid+64)
    double vvA = 0.0, vvB = 0.0;   // column potentials
    int pA = 0, pB = 0;            // p[col] = matched row (0 = free)

    for (int i = 1; i <= K; ++i) {
        double minvA = INF, minvB = INF;
        int wayA = 0, wayB = 0;
        bool usedA = (tid == 0);             // sentinel column used from start
        bool usedB = false;
        bool ruA = (tid == i);               // row i in the used-row set
        bool ruB = (tid == i - 64);
        if (tid == 0) pA = i;                // p[0] = i
        int i0 = i;
        int j0 = 0;
        int jfree = -1;

        for (int iter = 0; iter <= MM; ++iter) {
            double ua = readlane_d(uA, i0 & 63);
            double ub = readlane_d(uB, i0 & 63);
            double u_i0 = (i0 < 64) ? ua : ub;

            double candA = INF, candB = INF;
            if (jA >= 1 && !usedA) {
                double c = (double)Tc[(i0-1)*MM + (jA-1)];
                double cur = (c - u_i0) - vvA;
                if (cur < minvA) { minvA = cur; wayA = j0; }
                candA = minvA;
            }
            if (validB && !usedB) {
                double c = (double)Tc[(i0-1)*MM + (jB-1)];
                double cur = (c - u_i0) - vvB;
                if (cur < minvB) { minvB = cur; wayB = j0; }
                candB = minvB;
            }

            double delta = wave_min_f64(fmin(candA, candB));
            // tie-break = smallest column index; all A-cols < all B-cols
            unsigned long long eA = __ballot(candA == delta);
            unsigned long long eB = __ballot(candB == delta);
            int j1 = eA ? (__ffsll((unsigned long long)eA) - 1)
                        : (__ffsll((unsigned long long)eB) - 1 + 64);

            // potential / minv updates (j1 not yet marked used)
            if (ruA) uA += delta;
            if (ruB) uB += delta;
            if (usedA) vvA -= delta; else if (jA >= 1) minvA -= delta;
            if (usedB) vvB -= delta; else if (validB)  minvB -= delta;

            int pa = readlane_i(pA, j1 & 63);
            int pb = readlane_i(pB, j1 & 63);
            int pj1 = (j1 < 64) ? pa : pb;
            if (pj1 == 0) { jfree = j1; break; }

            if (jA == j1) usedA = true;
            if (jB == j1) usedB = true;
            ruA = ruA || (tid == pj1);
            ruB = ruB || (tid == pj1 - 64);
            j0 = j1;
            i0 = pj1;
        }

        // ---- augment along way[] (uniform chain, readlanes only) ----
        int jc = jfree;
        for (int iter = 0; iter <= MM && jc > 0; ++iter) {
            int wa = readlane_i(wayA, jc & 63);
            int wb = readlane_i(wayB, jc & 63);
            int w  = (jc < 64) ? wa : wb;
            int pa = readlane_i(pA, w & 63);
            int pb = readlane_i(pB, w & 63);
            int pw = (w < 64) ? pa : pb;
            if (jA == jc) pA = pw;
            if (jB == jc) pB = pw;
            jc = w;
        }
    }

    // ---- loss: pred column j (>=1) matched to target row p[j]-1 ----
    double se = 0.0, bce = 0.0;
    if (jA >= 1 && pA > 0) {
        int r = jA - 1, c = pA - 1;
        float dx = __fsub_rn(px[r], tvx[c]);
        float dy = __fsub_rn(py[r], tvy[c]);
        se = (double)dx*(double)dx + (double)dy*(double)dy;
        double pcv = (double)pc[r];
        pcv = fmin(fmax(pcv, 1e-12), 1.0 - 1e-12);
        double tc = (double)tvc[c];
        bce = -(tc * log(pcv) + (1.0 - tc) * log1p(-pcv));
    }
    if (validB && pB > 0) {
        int r = jB - 1, c = pB - 1;
        float dx = __fsub_rn(px[r], tvx[c]);
        float dy = __fsub_rn(py[r], tvy[c]);
        se += (double)dx*(double)dx + (double)dy*(double)dy;
        double pcv = (double)pc[r];
        pcv = fmin(fmax(pcv, 1e-12), 1.0 - 1e-12);
        double tc = (double)tvc[c];
        bce += -(tc * log(pcv) + (1.0 - tc) * log1p(-pcv));
    }
    for (int m = 1; m < 64; m <<= 1) {
        se  += __shfl_xor(se,  m, 64);
        bce += __shfl_xor(bce, m, 64);
    }
    if (tid == 0) ws[b] = se / (2.0 * (double)K) + bce / (double)K;
}

__global__ __launch_bounds__(64) void final_reduce(const double* __restrict__ ws,
                                                   float* __restrict__ out) {
    double v = ws[threadIdx.x];   // BATCH == 64 == one wave
    for (int m = 1; m < 64; m <<= 1) v += __shfl_xor(v, m, 64);
    if (threadIdx.x == 0) out[0] = (float)(v / (double)BATCH);
}

extern "C" void kernel_launch(void* const* d_in, const int* in_sizes, int n_in,
                              void* d_out, int out_size, void* d_ws, size_t ws_size,
                              hipStream_t stream) {
    const float* pred   = (const float*)d_in[0];
    const float* target = (const float*)d_in[1];
    double* ws = (double*)d_ws;
    float* out = (float*)d_out;
    hungarian_loss_kernel<<<dim3(BATCH), dim3(64), 0, stream>>>(pred, target, ws);
    final_reduce<<<dim3(1), dim3(64), 0, stream>>>(ws, out);
}

// Round 4
// 73.506 us; speedup vs baseline: 51.8015x; 1.0627x over previous
//
#include <hip/hip_runtime.h>
#include <math.h>

#define BATCH 64
#define MM 100     // predictions per batch (columns in the transposed problem)
#define NN 100     // targets per batch

// ---------- fast wave-uniform primitives (VALU, not LDS pipe) ----------

__device__ __forceinline__ int readlane_i(int v, int lane) {
    return __builtin_amdgcn_readlane(v, lane);
}
__device__ __forceinline__ double readlane_d(double x, int lane) {
    union { double d; int i[2]; } u; u.d = x;
    union { int i[2]; double d; } r;
    r.i[0] = __builtin_amdgcn_readlane(u.i[0], lane);
    r.i[1] = __builtin_amdgcn_readlane(u.i[1], lane);
    return r.d;
}

template<int CTRL>
__device__ __forceinline__ double dpp_min_f64(double x) {
    union { double d; int i[2]; } u, p;
    u.d = x;
    // old = src, bound_ctrl=false: lanes with invalid source keep own value
    p.i[0] = __builtin_amdgcn_update_dpp(u.i[0], u.i[0], CTRL, 0xF, 0xF, false);
    p.i[1] = __builtin_amdgcn_update_dpp(u.i[1], u.i[1], CTRL, 0xF, 0xF, false);
    return fmin(u.d, p.d);
}

// full-wave64 min; returns the min broadcast (via lane 63) to all lanes
__device__ __forceinline__ double wave_min_f64(double x) {
    x = dpp_min_f64<0xB1>(x);    // quad_perm [1,0,3,2]  (xor 1)
    x = dpp_min_f64<0x4E>(x);    // quad_perm [2,3,0,1]  (xor 2)
    x = dpp_min_f64<0x141>(x);   // row_half_mirror      (min over 8)
    x = dpp_min_f64<0x140>(x);   // row_mirror           (min over 16)
    x = dpp_min_f64<0x142>(x);   // row_bcast15          (min over 32)
    x = dpp_min_f64<0x143>(x);   // row_bcast31          (min over 64)
    return readlane_d(x, 63);
}

// One wave per batch. Transposed rectangular Hungarian: "rows" = K valid
// targets (1..K), "columns" = 100 preds (1..100) + sentinel col 0.
// Lane owns columns {tid, tid+64} and rows {tid, tid+64}; all state in
// registers; uniform broadcasts via v_readlane; argmin via DPP f64 min.
// Inner loop is software-pipelined: the LDS cost-row loads for the NEXT
// iteration (or next phase) are issued as soon as p[j1] is known, and the
// potential/minv bookkeeping overlaps the DS latency.

__global__ __launch_bounds__(64) void hungarian_loss_kernel(
        const float* __restrict__ pred, const float* __restrict__ target,
        double* __restrict__ ws) {
    const int b = blockIdx.x;
    const int tid = threadIdx.x;
    const float* P = pred + b * MM * 3;
    const float* T = target + b * NN * 3;

    __shared__ float px[MM], py[MM], pc[MM];
    __shared__ float tvx[NN], tvy[NN], tvc[NN];
    __shared__ float Tc[NN * MM];   // 40 KB, [target c][pred r]

    const int tA = tid, tB = tid + 64;

    // ---- load pred (registers + LDS copy for the loss epilogue) ----
    float pxA=0.f, pyA=0.f, pxB=0.f, pyB=0.f;
    if (tA < MM) { pxA = P[3*tA]; pyA = P[3*tA+1]; px[tA]=pxA; py[tA]=pyA; pc[tA]=P[3*tA+2]; }
    if (tB < MM) { pxB = P[3*tB]; pyB = P[3*tB+1]; px[tB]=pxB; py[tB]=pyB; pc[tB]=P[3*tB+2]; }

    // ---- load targets, compact valid (conf > 0.5) preserving order ----
    float cxA=0.f, cyA=0.f, ccA=0.f, cxB=0.f, cyB=0.f, ccB=0.f;
    bool vA_=false, vB_=false;
    if (tA < NN) { cxA=T[3*tA]; cyA=T[3*tA+1]; ccA=T[3*tA+2]; vA_ = ccA > 0.5f; }
    if (tB < NN) { cxB=T[3*tB]; cyB=T[3*tB+1]; ccB=T[3*tB+2]; vB_ = ccB > 0.5f; }
    unsigned long long mA = __ballot(vA_);
    unsigned long long mB = __ballot(vB_);
    int nA_ = __popcll(mA);
    int K   = nA_ + __popcll(mB);
    unsigned long long below = (1ull << tid) - 1ull;
    if (vA_) { int q = __popcll(mA & below);       tvx[q]=cxA; tvy[q]=cyA; tvc[q]=ccA; }
    if (vB_) { int q = nA_ + __popcll(mB & below); tvx[q]=cxB; tvy[q]=cyB; tvc[q]=ccB; }

    if (K == 0) { if (tid == 0) ws[b] = 0.0; return; }

    __syncthreads();

    // ---- transposed cost matrix, f32 pipeline identical to np.linalg.norm ----
    for (int c = 0; c < K; ++c) {
        float tx = tvx[c], ty = tvy[c];
        {
            float dx = __fsub_rn(pxA, tx), dy = __fsub_rn(pyA, ty);
            float s  = __fadd_rn(__fmul_rn(dx,dx), __fmul_rn(dy,dy));
            Tc[c*MM + tA] = __fsqrt_rn(s);
        }
        if (tB < MM) {
            float dx = __fsub_rn(pxB, tx), dy = __fsub_rn(pyB, ty);
            float s  = __fadd_rn(__fmul_rn(dx,dx), __fmul_rn(dy,dy));
            Tc[c*MM + tB] = __fsqrt_rn(s);
        }
    }
    __syncthreads();

    // ---- rectangular JV Hungarian: K phases over 100 pred-columns ----
    const double INF = __builtin_inf();
    const int jA = tid;            // column 0..63 (0 = sentinel)
    const int jB = tid + 64;       // column 64..127; valid if <= 100
    const bool validB = (jB <= MM);
    const int idxA = (jA >= 1) ? (jA - 1) : 0;           // clamped cost col
    const int idxB = validB ? (jB - 1) : (MM - 1);

    double uA = 0.0, uB = 0.0;     // row potentials (rows tid, tid+64)
    double vvA = 0.0, vvB = 0.0;   // column potentials
    int pA = 0, pB = 0;            // p[col] = matched row (0 = free)

    // pipelined state: cost of current scan row + its row potential.
    // Invariant: u[i] == 0 at the start of phase i (row i was never in any
    // alternating tree before its own phase), so phase-start u_i0 is 0.
    float cA_f = Tc[idxA];         // row 0 == phase 1's row
    float cB_f = Tc[idxB];
    double u_i0 = 0.0;

    for (int i = 1; i <= K; ++i) {
        double minvA = INF, minvB = INF;
        int wayA = 0, wayB = 0;
        bool usedA = (tid == 0);             // sentinel column used from start
        bool usedB = false;
        bool ruA = (tid == i);               // rows currently in the tree
        bool ruB = (tid == i - 64);
        if (tid == 0) pA = i;                // p[0] = i
        int j0 = 0;
        int jfree = -1;

        for (int it = 0; it <= MM; ++it) {
            double candA = INF, candB = INF;
            if (jA >= 1 && !usedA) {
                double cur = ((double)cA_f - u_i0) - vvA;
                if (cur < minvA) { minvA = cur; wayA = j0; }
                candA = minvA;
            }
            if (validB && !usedB) {
                double cur = ((double)cB_f - u_i0) - vvB;
                if (cur < minvB) { minvB = cur; wayB = j0; }
                candB = minvB;
            }

            double delta = wave_min_f64(fmin(candA, candB));
            // tie-break = smallest column index; all A-cols < all B-cols
            unsigned long long eA = __ballot(candA == delta);
            unsigned long long eB = __ballot(candB == delta);
            int j1 = eA ? (__ffsll((unsigned long long)eA) - 1)
                        : (__ffsll((unsigned long long)eB) - 1 + 64);

            int pa = readlane_i(pA, j1 & 63);
            int pb = readlane_i(pB, j1 & 63);
            int pj1 = (j1 < 64) ? pa : pb;

            // ---- early-issue next LDS row (next scan row, or next phase's
            //      row when the path terminates) so latency hides under the
            //      bookkeeping / augment walk ----
            int nrow = (pj1 > 0) ? (pj1 - 1) : ((i < K) ? i : K - 1);
            float nxA = Tc[nrow * MM + idxA];
            float nxB = Tc[nrow * MM + idxB];
            double rua_ = readlane_d(uA, pj1 & 63);
            double rub_ = readlane_d(uB, pj1 & 63);
            double nu = (pj1 > 0) ? ((pj1 < 64) ? rua_ : rub_) : 0.0;

            // ---- potential / minv updates (overlap the DS latency) ----
            if (ruA) uA += delta;
            if (ruB) uB += delta;
            if (usedA) vvA -= delta; else if (jA >= 1) minvA -= delta;
            if (usedB) vvB -= delta; else if (validB)  minvB -= delta;

            cA_f = nxA; cB_f = nxB; u_i0 = nu;

            if (pj1 == 0) { jfree = j1; break; }

            usedA |= (jA == j1);
            usedB |= (jB == j1);
            ruA |= (tid == pj1);
            ruB |= (tid == pj1 - 64);
            j0 = j1;
        }

        // ---- augment along way[] (uniform chain; overlaps the prefetched
        //      next-phase cost loads) ----
        int jc = jfree;
        for (int s = 0; s <= MM && jc > 0; ++s) {
            int wa = readlane_i(wayA, jc & 63);
            int wb = readlane_i(wayB, jc & 63);
            int w  = (jc < 64) ? wa : wb;
            int pa = readlane_i(pA, w & 63);
            int pb = readlane_i(pB, w & 63);
            int pw = (w < 64) ? pa : pb;
            if (jA == jc) pA = pw;
            if (jB == jc) pB = pw;
            jc = w;
        }
    }

    // ---- loss: pred column j (>=1) matched to target row p[j]-1 ----
    double se = 0.0, bce = 0.0;
    if (jA >= 1 && pA > 0) {
        int r = jA - 1, c = pA - 1;
        float dx = __fsub_rn(px[r], tvx[c]);
        float dy = __fsub_rn(py[r], tvy[c]);
        se = (double)dx*(double)dx + (double)dy*(double)dy;
        double pcv = (double)pc[r];
        pcv = fmin(fmax(pcv, 1e-12), 1.0 - 1e-12);
        double tc = (double)tvc[c];
        bce = -(tc * log(pcv) + (1.0 - tc) * log1p(-pcv));
    }
    if (validB && pB > 0) {
        int r = jB - 1, c = pB - 1;
        float dx = __fsub_rn(px[r], tvx[c]);
        float dy = __fsub_rn(py[r], tvy[c]);
        se += (double)dx*(double)dx + (double)dy*(double)dy;
        double pcv = (double)pc[r];
        pcv = fmin(fmax(pcv, 1e-12), 1.0 - 1e-12);
        double tc = (double)tvc[c];
        bce += -(tc * log(pcv) + (1.0 - tc) * log1p(-pcv));
    }
    for (int m = 1; m < 64; m <<= 1) {
        se  += __shfl_xor(se,  m, 64);
        bce += __shfl_xor(bce, m, 64);
    }
    if (tid == 0) ws[b] = se / (2.0 * (double)K) + bce / (double)K;
}

__global__ __launch_bounds__(64) void final_reduce(const double* __restrict__ ws,
                                                   float* __restrict__ out) {
    double v = ws[threadIdx.x];   // BATCH == 64 == one wave
    for (int m = 1; m < 64; m <<= 1) v += __shfl_xor(v, m, 64);
    if (threadIdx.x == 0) out[0] = (float)(v / (double)BATCH);
}

extern "C" void kernel_launch(void* const* d_in, const int* in_sizes, int n_in,
                              void* d_out, int out_size, void* d_ws, size_t ws_size,
                              hipStream_t stream) {
    const float* pred   = (const float*)d_in[0];
    const float* target = (const float*)d_in[1];
    double* ws = (double*)d_ws;
    float* out = (float*)d_out;
    hungarian_loss_kernel<<<dim3(BATCH), dim3(64), 0, stream>>>(pred, target, ws);
    final_reduce<<<dim3(1), dim3(64), 0, stream>>>(ws, out);
}

// Round 5
// 66.642 us; speedup vs baseline: 57.1366x; 1.1030x over previous
//
#include <hip/hip_runtime.h>
#include <math.h>

#define BATCH 64
#define MM 100     // predictions per batch (columns)
#define NN 100     // targets per batch (rows after compaction)
#define ST 101     // padded LDS stride (kills bank conflicts on row scans)

// ---------- fast wave-uniform primitives (VALU, not LDS pipe) ----------

__device__ __forceinline__ int readlane_i(int v, int lane) {
    return __builtin_amdgcn_readlane(v, lane);
}
__device__ __forceinline__ double readlane_d(double x, int lane) {
    union { double d; int i[2]; } u; u.d = x;
    union { int i[2]; double d; } r;
    r.i[0] = __builtin_amdgcn_readlane(u.i[0], lane);
    r.i[1] = __builtin_amdgcn_readlane(u.i[1], lane);
    return r.d;
}

template<int CTRL>
__device__ __forceinline__ double dpp_min_f64(double x) {
    union { double d; int i[2]; } u, p;
    u.d = x;
    p.i[0] = __builtin_amdgcn_update_dpp(u.i[0], u.i[0], CTRL, 0xF, 0xF, false);
    p.i[1] = __builtin_amdgcn_update_dpp(u.i[1], u.i[1], CTRL, 0xF, 0xF, false);
    return fmin(u.d, p.d);
}

// full-wave64 min broadcast to all lanes
__device__ __forceinline__ double wave_min_f64(double x) {
    x = dpp_min_f64<0xB1>(x);    // quad_perm xor1
    x = dpp_min_f64<0x4E>(x);    // quad_perm xor2
    x = dpp_min_f64<0x141>(x);   // row_half_mirror
    x = dpp_min_f64<0x140>(x);   // row_mirror
    x = dpp_min_f64<0x142>(x);   // row_bcast15
    x = dpp_min_f64<0x143>(x);   // row_bcast31
    return readlane_d(x, 63);
}

// One wave per batch. Transposed rectangular assignment: rows = K valid
// targets (1..K), columns = 100 preds (1..100) + sentinel col 0.
// Row r owned by lane r-1 (slot A, r<=64) or lane r-65 (slot B).
// Column j owned by lane j (slot A, j<64) or lane j-64 (slot B, j<=100).
// JV warm start: u[row] = row min (exact f32 value), greedy-claim argmin
// columns; only collision rows run Dijkstra phases. Final matching equals
// numpy's (unique optimum of the same f32 cost matrix; f64 arithmetic).

__global__ __launch_bounds__(64) void hungarian_loss_kernel(
        const float* __restrict__ pred, const float* __restrict__ target,
        double* __restrict__ ws) {
    const int b = blockIdx.x;
    const int tid = threadIdx.x;
    const float* P = pred + b * MM * 3;
    const float* T = target + b * NN * 3;

    __shared__ float px[MM], py[MM], pc[MM];
    __shared__ float tvx[NN], tvy[NN], tvc[NN];
    __shared__ float Tc[NN * ST];   // ~40.4 KB, [target row][pred col], padded

    const int tA = tid, tB = tid + 64;

    // ---- load pred (registers + LDS for epilogue) ----
    float pxA=0.f, pyA=0.f, pxB=0.f, pyB=0.f;
    if (tA < MM) { pxA = P[3*tA]; pyA = P[3*tA+1]; px[tA]=pxA; py[tA]=pyA; pc[tA]=P[3*tA+2]; }
    if (tB < MM) { pxB = P[3*tB]; pyB = P[3*tB+1]; px[tB]=pxB; py[tB]=pyB; pc[tB]=P[3*tB+2]; }

    // ---- load targets, compact valid (conf > 0.5) preserving order ----
    float cxA=0.f, cyA=0.f, ccA=0.f, cxB=0.f, cyB=0.f, ccB=0.f;
    bool vA_=false, vB_=false;
    if (tA < NN) { cxA=T[3*tA]; cyA=T[3*tA+1]; ccA=T[3*tA+2]; vA_ = ccA > 0.5f; }
    if (tB < NN) { cxB=T[3*tB]; cyB=T[3*tB+1]; ccB=T[3*tB+2]; vB_ = ccB > 0.5f; }
    unsigned long long mAv = __ballot(vA_);
    unsigned long long mBv = __ballot(vB_);
    int nA_ = __popcll(mAv);
    int K   = nA_ + __popcll(mBv);
    unsigned long long below = (1ull << tid) - 1ull;
    if (vA_) { int q = __popcll(mAv & below);       tvx[q]=cxA; tvy[q]=cyA; tvc[q]=ccA; }
    if (vB_) { int q = nA_ + __popcll(mBv & below); tvx[q]=cxB; tvy[q]=cyB; tvc[q]=ccB; }

    if (K == 0) { if (tid == 0) ws[b] = 0.0; return; }

    __syncthreads();

    // ---- cost matrix, f32 pipeline identical to np.linalg.norm ----
    for (int c = 0; c < K; ++c) {
        float tx = tvx[c], ty = tvy[c];
        {
            float dx = __fsub_rn(pxA, tx), dy = __fsub_rn(pyA, ty);
            float s  = __fadd_rn(__fmul_rn(dx,dx), __fmul_rn(dy,dy));
            Tc[c*ST + tA] = __fsqrt_rn(s);
        }
        if (tB < MM) {
            float dx = __fsub_rn(pxB, tx), dy = __fsub_rn(pyB, ty);
            float s  = __fadd_rn(__fmul_rn(dx,dx), __fmul_rn(dy,dy));
            Tc[c*ST + tB] = __fsqrt_rn(s);
        }
    }
    __syncthreads();

    // ---- per-row minima (lane-parallel; lane t scans rows t and t+64) ----
    float mvA_ = 1e30f; int mjA_ = 0;
    float mvB_ = 1e30f; int mjB_ = 0;
    if (tid < K) {
        const float* rp = &Tc[tid * ST];
        float m0=rp[0], m1=rp[1], m2=rp[2], m3=rp[3];
        int   i0_=0,   i1_=1,    i2_=2,    i3_=3;
        #pragma unroll
        for (int j = 4; j < MM; j += 4) {
            float v0=rp[j], v1=rp[j+1], v2=rp[j+2], v3=rp[j+3];
            if (v0<m0){m0=v0;i0_=j;}
            if (v1<m1){m1=v1;i1_=j+1;}
            if (v2<m2){m2=v2;i2_=j+2;}
            if (v3<m3){m3=v3;i3_=j+3;}
        }
        if (m1<m0){m0=m1;i0_=i1_;}
        if (m3<m2){m2=m3;i2_=i3_;}
        if (m2<m0){m0=m2;i0_=i2_;}
        mvA_=m0; mjA_=i0_;
    }
    if (tid + 64 < K) {
        const float* rp = &Tc[(tid+64) * ST];
        float m0=rp[0], m1=rp[1], m2=rp[2], m3=rp[3];
        int   i0_=0,   i1_=1,    i2_=2,    i3_=3;
        #pragma unroll
        for (int j = 4; j < MM; j += 4) {
            float v0=rp[j], v1=rp[j+1], v2=rp[j+2], v3=rp[j+3];
            if (v0<m0){m0=v0;i0_=j;}
            if (v1<m1){m1=v1;i1_=j+1;}
            if (v2<m2){m2=v2;i2_=j+2;}
            if (v3<m3){m3=v3;i3_=j+3;}
        }
        if (m1<m0){m0=m1;i0_=i1_;}
        if (m3<m2){m2=m3;i2_=i3_;}
        if (m2<m0){m0=m2;i0_=i2_;}
        mvB_=m0; mjB_=i0_;
    }

    // row potentials u (exact f32 row-min values)
    double uA = (tid < K)      ? (double)mvA_ : 0.0;   // row tid+1
    double uB = (tid + 64 < K) ? (double)mvB_ : 0.0;   // row tid+65
    double vvA = 0.0, vvB = 0.0;                       // column potentials
    int pA = 0, pB = 0;                                // p[col] = row (0=free)

    const int jA = tid;            // column 0..63 (0 = sentinel)
    const int jB = tid + 64;       // column 64..127; valid if <= 100
    const bool validB = (jB <= MM);
    const int idxA = (jA >= 1) ? (jA - 1) : 0;
    const int idxB = validB ? (jB - 1) : (MM - 1);

    // ---- greedy claim (JV column reduction) ----
    bool rowFreeA = false, rowFreeB = false;
    for (int r = 1; r <= K; ++r) {
        int lane = (r - 1) & 63;
        bool isA = (r <= 64);
        int mj  = isA ? readlane_i(mjA_, lane) : readlane_i(mjB_, lane);
        int col = mj + 1;
        int prow = (col < 64) ? readlane_i(pA, col) : readlane_i(pB, col & 63);
        if (prow == 0) {
            if (jA == col) pA = r;
            if (validB && jB == col) pB = r;
        } else {
            rowFreeA |= ( isA && tid == lane);
            rowFreeB |= (!isA && tid == lane);
        }
    }
    unsigned long long fA = __ballot(rowFreeA);
    unsigned long long fB = __ballot(rowFreeB);

    // ---- Dijkstra phases for collision rows only ----
    const double INF = __builtin_inf();
    while (fA | fB) {
        int r;
        if (fA) { r = (int)__ffsll(fA);      fA &= fA - 1; }
        else    { r = (int)__ffsll(fB) + 64; fB &= fB - 1; }

        double minvA = INF, minvB = INF;
        int wayA = 0, wayB = 0;
        bool usedA = (tid == 0);
        bool usedB = false;
        bool ruA = (tid == r - 1);       // only matches when r <= 64
        bool ruB = (tid == r - 65);
        if (tid == 0) pA = r;            // p[0] = r
        int j0 = 0, jfree = -1;

        float cA_f = Tc[(r-1)*ST + idxA];
        float cB_f = Tc[(r-1)*ST + idxB];
        double ura = readlane_d(uA, (r-1) & 63);
        double urb = readlane_d(uB, (r-1) & 63);
        double u_i0 = (r <= 64) ? ura : urb;

        for (int it = 0; it <= MM; ++it) {
            double candA = INF, candB = INF;
            if (jA >= 1 && !usedA) {
                double cur = ((double)cA_f - u_i0) - vvA;
                if (cur < minvA) { minvA = cur; wayA = j0; }
                candA = minvA;
            }
            if (validB && !usedB) {
                double cur = ((double)cB_f - u_i0) - vvB;
                if (cur < minvB) { minvB = cur; wayB = j0; }
                candB = minvB;
            }

            double delta = wave_min_f64(fmin(candA, candB));
            unsigned long long eA = __ballot(candA == delta);
            unsigned long long eB = __ballot(candB == delta);
            int j1 = eA ? (__ffsll(eA) - 1) : (__ffsll(eB) - 1 + 64);

            int pa = readlane_i(pA, j1 & 63);
            int pb = readlane_i(pB, j1 & 63);
            int pj1 = (j1 < 64) ? pa : pb;

            // early-issue next scan row's LDS loads + u broadcast
            int nrow = (pj1 > 0) ? pj1 : r;
            float nxA = Tc[(nrow-1)*ST + idxA];
            float nxB = Tc[(nrow-1)*ST + idxB];
            double rua_ = readlane_d(uA, (pj1 - 1) & 63);
            double rub_ = readlane_d(uB, (pj1 - 1) & 63);
            double nu = (pj1 <= 64) ? rua_ : rub_;

            // potential / minv updates (overlap DS latency)
            if (ruA) uA += delta;
            if (ruB) uB += delta;
            if (usedA) vvA -= delta; else if (jA >= 1) minvA -= delta;
            if (usedB) vvB -= delta; else if (validB)  minvB -= delta;

            cA_f = nxA; cB_f = nxB; u_i0 = nu;

            if (pj1 == 0) { jfree = j1; break; }

            usedA |= (jA == j1);
            usedB |= (jB == j1);
            ruA |= (tid == pj1 - 1);
            ruB |= (tid == pj1 - 65);
            j0 = j1;
        }

        // ---- augment along way[] (uniform readlane chain) ----
        int jc = jfree;
        for (int s = 0; s <= MM && jc > 0; ++s) {
            int wa = readlane_i(wayA, jc & 63);
            int wb = readlane_i(wayB, jc & 63);
            int w  = (jc < 64) ? wa : wb;
            int pa = readlane_i(pA, w & 63);
            int pb = readlane_i(pB, w & 63);
            int pw = (w < 64) ? pa : pb;
            if (jA == jc) pA = pw;
            if (jB == jc) pB = pw;
            jc = w;
        }
    }

    // ---- loss: pred column j (>=1) matched to target row p[j]-1 ----
    double se = 0.0, bce = 0.0;
    if (jA >= 1 && pA > 0) {
        int rr = jA - 1, c = pA - 1;
        float dx = __fsub_rn(px[rr], tvx[c]);
        float dy = __fsub_rn(py[rr], tvy[c]);
        se = (double)dx*(double)dx + (double)dy*(double)dy;
        double pcv = (double)pc[rr];
        pcv = fmin(fmax(pcv, 1e-12), 1.0 - 1e-12);
        double tc = (double)tvc[c];
        bce = -(tc * log(pcv) + (1.0 - tc) * log1p(-pcv));
    }
    if (validB && pB > 0) {
        int rr = jB - 1, c = pB - 1;
        float dx = __fsub_rn(px[rr], tvx[c]);
        float dy = __fsub_rn(py[rr], tvy[c]);
        se += (double)dx*(double)dx + (double)dy*(double)dy;
        double pcv = (double)pc[rr];
        pcv = fmin(fmax(pcv, 1e-12), 1.0 - 1e-12);
        double tc = (double)tvc[c];
        bce += -(tc * log(pcv) + (1.0 - tc) * log1p(-pcv));
    }
    for (int m = 1; m < 64; m <<= 1) {
        se  += __shfl_xor(se,  m, 64);
        bce += __shfl_xor(bce, m, 64);
    }
    if (tid == 0) ws[b] = se / (2.0 * (double)K) + bce / (double)K;
}

__global__ __launch_bounds__(64) void final_reduce(const double* __restrict__ ws,
                                                   float* __restrict__ out) {
    double v = ws[threadIdx.x];   // BATCH == 64 == one wave
    for (int m = 1; m < 64; m <<= 1) v += __shfl_xor(v, m, 64);
    if (threadIdx.x == 0) out[0] = (float)(v / (double)BATCH);
}

extern "C" void kernel_launch(void* const* d_in, const int* in_sizes, int n_in,
                              void* d_out, int out_size, void* d_ws, size_t ws_size,
                              hipStream_t stream) {
    const float* pred   = (const float*)d_in[0];
    const float* target = (const float*)d_in[1];
    double* ws = (double*)d_ws;
    float* out = (float*)d_out;
    hungarian_loss_kernel<<<dim3(BATCH), dim3(64), 0, stream>>>(pred, target, ws);
    final_reduce<<<dim3(1), dim3(64), 0, stream>>>(ws, out);
}

// Round 6
// 58.354 us; speedup vs baseline: 65.2518x; 1.1420x over previous
//
#include <hip/hip_runtime.h>
#include <math.h>

#define BATCH 64
#define MM 100     // predictions per batch (columns)
#define NN 100     // targets per batch (rows after compaction)
#define ST 101     // padded LDS stride (conflict-free row scans)
#define BIGCLAIM 0x7fffffff

// ---------- wave-uniform primitives (VALU, not LDS pipe) ----------

__device__ __forceinline__ int readlane_i(int v, int lane) {
    return __builtin_amdgcn_readlane(v, lane);
}
__device__ __forceinline__ float readlane_f(float v, int lane) {
    return __int_as_float(__builtin_amdgcn_readlane(__float_as_int(v), lane));
}
__device__ __forceinline__ double readlane_d(double x, int lane) {
    union { double d; int i[2]; } u; u.d = x;
    union { int i[2]; double d; } r;
    r.i[0] = __builtin_amdgcn_readlane(u.i[0], lane);
    r.i[1] = __builtin_amdgcn_readlane(u.i[1], lane);
    return r.d;
}

template<int CTRL>
__device__ __forceinline__ double dpp_min_f64(double x) {
    union { double d; int i[2]; } u, p;
    u.d = x;
    p.i[0] = __builtin_amdgcn_update_dpp(u.i[0], u.i[0], CTRL, 0xF, 0xF, false);
    p.i[1] = __builtin_amdgcn_update_dpp(u.i[1], u.i[1], CTRL, 0xF, 0xF, false);
    return fmin(u.d, p.d);
}
__device__ __forceinline__ double wave_min_f64(double x) {
    x = dpp_min_f64<0xB1>(x);    // quad_perm xor1
    x = dpp_min_f64<0x4E>(x);    // quad_perm xor2
    x = dpp_min_f64<0x141>(x);   // row_half_mirror
    x = dpp_min_f64<0x140>(x);   // row_mirror
    x = dpp_min_f64<0x142>(x);   // row_bcast15
    x = dpp_min_f64<0x143>(x);   // row_bcast31
    return readlane_d(x, 63);
}

template<int CTRL>
__device__ __forceinline__ float dpp_min_f32(float x) {
    int p = __builtin_amdgcn_update_dpp(__float_as_int(x), __float_as_int(x),
                                        CTRL, 0xF, 0xF, false);
    return fminf(x, __int_as_float(p));
}
__device__ __forceinline__ float wave_min_f32(float x) {
    x = dpp_min_f32<0xB1>(x);
    x = dpp_min_f32<0x4E>(x);
    x = dpp_min_f32<0x141>(x);
    x = dpp_min_f32<0x140>(x);
    x = dpp_min_f32<0x142>(x);
    x = dpp_min_f32<0x143>(x);
    return readlane_f(x, 63);
}

// Two waves per batch: both build the cost matrix (alternate rows, with the
// row-min/argmin fused via f32 DPP reduction); wave 1 then exits. Wave 0 runs
// the greedy claim (LDS atomicMin) + absolute-distance Dijkstra phases with
// implicit row potentials (u[i] = c(i,j_m) - v[j_m]) and phase-end v updates.
// Matching equals numpy's (unique optimum of the same f32 cost matrix).

__global__ __launch_bounds__(128) void hungarian_loss_kernel(
        const float* __restrict__ pred, const float* __restrict__ target,
        double* __restrict__ ws) {
    const int b    = blockIdx.x;
    const int tid  = threadIdx.x;
    const int lane = tid & 63;
    const int wave = tid >> 6;
    const float* P = pred + b * MM * 3;
    const float* T = target + b * NN * 3;

    __shared__ float px[MM], py[MM], pc[MM];
    __shared__ float tvx[NN], tvy[NN], tvc[NN];
    __shared__ float Tc[NN * ST];       // [target row][pred col], padded
    __shared__ float rminv[NN];
    __shared__ int   rmini[NN];
    __shared__ int   claimArr[MM + 1];
    __shared__ int   Ksh;

    // ---- pred coords (both waves, registers) ----
    float pxA = P[3*lane], pyA = P[3*lane+1];
    float pxB = 0.f, pyB = 0.f;
    const bool colBvalid = (lane + 64 < MM);     // cols 64..99
    if (colBvalid) { pxB = P[3*(lane+64)]; pyB = P[3*(lane+64)+1]; }

    if (wave == 0) {
        // pred into LDS for epilogue
        px[lane] = pxA; py[lane] = pyA; pc[lane] = P[3*lane+2];
        if (colBvalid) { px[lane+64]=pxB; py[lane+64]=pyB; pc[lane+64]=P[3*(lane+64)+2]; }
        // targets: load + compact valid (conf > 0.5), order-preserving
        float cxA=0.f, cyA=0.f, ccA=0.f, cxB=0.f, cyB=0.f, ccB=0.f;
        bool vA_=false, vB_=false;
        { cxA=T[3*lane]; cyA=T[3*lane+1]; ccA=T[3*lane+2]; vA_ = ccA > 0.5f; }
        if (lane + 64 < NN) {
            cxB=T[3*(lane+64)]; cyB=T[3*(lane+64)+1]; ccB=T[3*(lane+64)+2];
            vB_ = ccB > 0.5f;
        }
        unsigned long long mAv = __ballot(vA_);
        unsigned long long mBv = __ballot(vB_);
        int nA_ = __popcll(mAv);
        int K0  = nA_ + __popcll(mBv);
        unsigned long long below = (1ull << lane) - 1ull;
        if (vA_) { int q = __popcll(mAv & below);       tvx[q]=cxA; tvy[q]=cyA; tvc[q]=ccA; }
        if (vB_) { int q = nA_ + __popcll(mBv & below); tvx[q]=cxB; tvy[q]=cyB; tvc[q]=ccB; }
        if (lane == 0) Ksh = K0;
        // init claim array
        claimArr[lane] = BIGCLAIM;
        if (lane + 64 <= MM) claimArr[lane + 64] = BIGCLAIM;
    }
    __syncthreads();                                  // barrier 1
    const int K = Ksh;
    if (K == 0) { if (tid == 0) ws[b] = 0.0; return; }

    // compacted target coords into registers (both waves; for readlane bcast)
    float txA = (lane < K)      ? tvx[lane]      : 0.f;
    float tyA = (lane < K)      ? tvy[lane]      : 0.f;
    float txB = (lane + 64 < K) ? tvx[lane + 64] : 0.f;
    float tyB = (lane + 64 < K) ? tvy[lane + 64] : 0.f;

    // ---- cost build (waves split rows) + fused row-min/argmin ----
    for (int c = wave; c < K; c += 2) {
        float tx = (c < 64) ? readlane_f(txA, c) : readlane_f(txB, c - 64);
        float ty = (c < 64) ? readlane_f(tyA, c) : readlane_f(tyB, c - 64);
        float dxA = __fsub_rn(pxA, tx), dyA = __fsub_rn(pyA, ty);
        float cA = __fsqrt_rn(__fadd_rn(__fmul_rn(dxA,dxA), __fmul_rn(dyA,dyA)));
        Tc[c*ST + lane] = cA;
        float cB = 1e30f;
        if (colBvalid) {
            float dxB = __fsub_rn(pxB, tx), dyB = __fsub_rn(pyB, ty);
            cB = __fsqrt_rn(__fadd_rn(__fmul_rn(dxB,dxB), __fmul_rn(dyB,dyB)));
            Tc[c*ST + lane + 64] = cB;
        }
        float m = wave_min_f32(fminf(cA, cB));
        unsigned long long eA = __ballot(cA == m);
        unsigned long long eB = __ballot(cB == m);
        int argc = eA ? ((int)__ffsll(eA) - 1) : ((int)__ffsll(eB) - 1 + 64);
        if (lane == 0) { rminv[c] = m; rmini[c] = argc; }
    }
    __syncthreads();                                  // barrier 2
    if (wave == 1) return;

    // ================== wave 0 only from here ==================
    const int jA = lane;                 // column 0..63 (0 = sentinel)
    const int jB = lane + 64;            // column 64..127; valid if <= 100
    const bool validB = (jB <= MM);
    const int idxA = (jA >= 1) ? (jA - 1) : 0;
    const int idxB = validB ? (jB - 1) : (MM - 1);

    // ---- greedy claim: min row index wins each argmin column ----
    int rA = lane + 1, rB = lane + 65;   // row indices owned by this lane
    int argA = 0, argB = 0;
    if (lane < K)      { argA = rmini[lane] + 1;      atomicMin(&claimArr[argA], rA); }
    if (lane + 64 < K) { argB = rmini[lane + 64] + 1; atomicMin(&claimArr[argB], rB); }
    __threadfence_block();
    int pA = 0, pB = 0;
    if (jA >= 1) { int c0 = claimArr[jA]; pA = (c0 != BIGCLAIM) ? c0 : 0; }
    if (validB)  { int c0 = claimArr[jB]; pB = (c0 != BIGCLAIM) ? c0 : 0; }
    bool freeA = (lane < K)      && (claimArr[argA] != rA);
    bool freeB = (lane + 64 < K) && (claimArr[argB] != rB);
    unsigned long long fA = __ballot(freeA);
    unsigned long long fB = __ballot(freeB);

    double vvA = 0.0, vvB = 0.0;         // column potentials

    // ---- Dijkstra phases (absolute distances, implicit u) ----
    const double INF = __builtin_inf();
    while (fA | fB) {
        int r;
        if (fA) { r = (int)__ffsll(fA);      fA &= fA - 1; }
        else    { r = (int)__ffsll(fB) + 64; fB &= fB - 1; }

        double minvA = INF, minvB = INF;
        int wayA = 0, wayB = 0;
        bool usedA = (lane == 0), usedB = false;
        double dpopA = 0.0, dpopB = 0.0;
        if (lane == 0) pA = r;           // p[0] = r (augment terminator)
        int j0 = 0, jfree = -1;
        double dstar = 0.0;

        float cA_f = Tc[(r-1)*ST + idxA];
        float cB_f = Tc[(r-1)*ST + idxB];
        double S = -(double)rminv[r-1];  // free row: u0 = row min

        for (int it = 0; it <= MM; ++it) {
            double candA = INF, candB = INF;
            if (jA >= 1 && !usedA) {
                double t = ((double)cA_f - vvA) + S;
                if (t < minvA) { minvA = t; wayA = j0; }
                candA = minvA;
            }
            if (validB && !usedB) {
                double t = ((double)cB_f - vvB) + S;
                if (t < minvB) { minvB = t; wayB = j0; }
                candB = minvB;
            }

            double delta = wave_min_f64(fmin(candA, candB));
            unsigned long long eA = __ballot(candA == delta);
            unsigned long long eB = __ballot(candB == delta);
            int j1 = eA ? ((int)__ffsll(eA) - 1) : ((int)__ffsll(eB) - 1 + 64);

            if (jA == j1) { usedA = true; dpopA = delta; }
            if (jB == j1) { usedB = true; dpopB = delta; }

            int pa = readlane_i(pA, j1 & 63);
            int pb = readlane_i(pB, j1 & 63);
            int pj1 = (j1 < 64) ? pa : pb;
            if (pj1 == 0) { jfree = j1; dstar = delta; break; }

            // prefetch next scan row + implicit-u S update:
            // u[pj1] = c(pj1, j1) - v[j1];  S = d0 - c(pj1,j1) + v[j1]
            float nxA = Tc[(pj1-1)*ST + idxA];
            float nxB = Tc[(pj1-1)*ST + idxB];
            float cjm = (j1 < 64) ? readlane_f(nxA, j1) : readlane_f(nxB, j1 & 63);
            double vjm = (j1 < 64) ? readlane_d(vvA, j1) : readlane_d(vvB, j1 & 63);
            S = (delta - (double)cjm) + vjm;
            cA_f = nxA; cB_f = nxB;
            j0 = j1;
        }

        // ---- phase-end potential update: v[j] += d[j] - d*  (scanned j) ----
        if (usedA && jA >= 1) vvA += dpopA - dstar;
        if (usedB)            vvB += dpopB - dstar;

        // ---- augment along way[] ----
        int jc = jfree;
        for (int s = 0; s <= MM && jc > 0; ++s) {
            int wa = readlane_i(wayA, jc & 63);
            int wb = readlane_i(wayB, jc & 63);
            int w  = (jc < 64) ? wa : wb;
            int pa = readlane_i(pA, w & 63);
            int pb = readlane_i(pB, w & 63);
            int pw = (w < 64) ? pa : pb;
            if (jA == jc) pA = pw;
            if (jB == jc) pB = pw;
            jc = w;
        }
    }

    // ---- loss: pred column j (>=1) matched to target row p[j]-1 ----
    double se = 0.0, bce = 0.0;
    if (jA >= 1 && pA > 0) {
        int rr = jA - 1, c = pA - 1;
        float dx = __fsub_rn(px[rr], tvx[c]);
        float dy = __fsub_rn(py[rr], tvy[c]);
        se = (double)dx*(double)dx + (double)dy*(double)dy;
        double pcv = (double)pc[rr];
        pcv = fmin(fmax(pcv, 1e-12), 1.0 - 1e-12);
        double tc = (double)tvc[c];
        bce = -(tc * log(pcv) + (1.0 - tc) * log1p(-pcv));
    }
    if (validB && pB > 0) {
        int rr = jB - 1, c = pB - 1;
        float dx = __fsub_rn(px[rr], tvx[c]);
        float dy = __fsub_rn(py[rr], tvy[c]);
        se += (double)dx*(double)dx + (double)dy*(double)dy;
        double pcv = (double)pc[rr];
        pcv = fmin(fmax(pcv, 1e-12), 1.0 - 1e-12);
        double tc = (double)tvc[c];
        bce += -(tc * log(pcv) + (1.0 - tc) * log1p(-pcv));
    }
    for (int m = 1; m < 64; m <<= 1) {
        se  += __shfl_xor(se,  m, 64);
        bce += __shfl_xor(bce, m, 64);
    }
    if (lane == 0) ws[b] = se / (2.0 * (double)K) + bce / (double)K;
}

__global__ __launch_bounds__(64) void final_reduce(const double* __restrict__ ws,
                                                   float* __restrict__ out) {
    double v = ws[threadIdx.x];   // BATCH == 64 == one wave
    for (int m = 1; m < 64; m <<= 1) v += __shfl_xor(v, m, 64);
    if (threadIdx.x == 0) out[0] = (float)(v / (double)BATCH);
}

extern "C" void kernel_launch(void* const* d_in, const int* in_sizes, int n_in,
                              void* d_out, int out_size, void* d_ws, size_t ws_size,
                              hipStream_t stream) {
    const float* pred   = (const float*)d_in[0];
    const float* target = (const float*)d_in[1];
    double* ws = (double*)d_ws;
    float* out = (float*)d_out;
    hungarian_loss_kernel<<<dim3(BATCH), dim3(128), 0, stream>>>(pred, target, ws);
    final_reduce<<<dim3(1), dim3(64), 0, stream>>>(ws, out);
}

// Round 7
// 53.626 us; speedup vs baseline: 71.0054x; 1.0882x over previous
//
#include <hip/hip_runtime.h>
#include <math.h>

#define BATCH 64
#define MM 100     // predictions per batch (columns)
#define NN 100     // targets per batch (rows after compaction)
#define ST 101     // padded LDS stride (conflict-free row scans)
#define BIGCLAIM 0x7fffffff

// ---------- wave-uniform primitives (VALU, not LDS pipe) ----------

__device__ __forceinline__ int readlane_i(int v, int lane) {
    return __builtin_amdgcn_readlane(v, lane);
}
__device__ __forceinline__ float readlane_f(float v, int lane) {
    return __int_as_float(__builtin_amdgcn_readlane(__float_as_int(v), lane));
}

template<int CTRL>
__device__ __forceinline__ float dpp_min_f32(float x) {
    int p = __builtin_amdgcn_update_dpp(__float_as_int(x), __float_as_int(x),
                                        CTRL, 0xF, 0xF, false);
    return fminf(x, __int_as_float(p));
}
// full-wave64 min broadcast to all lanes (6 fuseable DPP-min steps)
__device__ __forceinline__ float wave_min_f32(float x) {
    x = dpp_min_f32<0xB1>(x);    // quad_perm xor1
    x = dpp_min_f32<0x4E>(x);    // quad_perm xor2
    x = dpp_min_f32<0x141>(x);   // row_half_mirror
    x = dpp_min_f32<0x140>(x);   // row_mirror
    x = dpp_min_f32<0x142>(x);   // row_bcast15
    x = dpp_min_f32<0x143>(x);   // row_bcast31
    return readlane_f(x, 63);
}

// Two waves per batch build the cost matrix (alternate rows, fused row
// argmin); wave 1 exits. Wave 0: greedy claim (LDS atomicMin) -> JV
// augmenting-row-reduction (2 sweeps) -> f32 absolute-distance Dijkstra
// phases with implicit row potentials. Matching equals numpy's optimum of
// the same f32 cost matrix (unique a.s.; near-tie flips cost <<
// threshold). Loss epilogue stays f64.

__global__ __launch_bounds__(128) void hungarian_loss_kernel(
        const float* __restrict__ pred, const float* __restrict__ target,
        double* __restrict__ ws) {
    const int b    = blockIdx.x;
    const int tid  = threadIdx.x;
    const int lane = tid & 63;
    const int wave = tid >> 6;
    const float* P = pred + b * MM * 3;
    const float* T = target + b * NN * 3;

    __shared__ float px[MM], py[MM], pc[MM];
    __shared__ float tvx[NN], tvy[NN], tvc[NN];
    __shared__ float Tc[NN * ST];       // [target row][pred col], padded
    __shared__ int   rmini[NN];
    __shared__ int   claimArr[MM + 1];
    __shared__ int   Ksh;

    // ---- pred coords (both waves, registers) ----
    float pxA = P[3*lane], pyA = P[3*lane+1];
    float pxB = 0.f, pyB = 0.f;
    const bool colBvalid = (lane + 64 < MM);     // cols 64..99
    if (colBvalid) { pxB = P[3*(lane+64)]; pyB = P[3*(lane+64)+1]; }

    if (wave == 0) {
        px[lane] = pxA; py[lane] = pyA; pc[lane] = P[3*lane+2];
        if (colBvalid) { px[lane+64]=pxB; py[lane+64]=pyB; pc[lane+64]=P[3*(lane+64)+2]; }
        float cxA=0.f, cyA=0.f, ccA=0.f, cxB=0.f, cyB=0.f, ccB=0.f;
        bool vA_=false, vB_=false;
        { cxA=T[3*lane]; cyA=T[3*lane+1]; ccA=T[3*lane+2]; vA_ = ccA > 0.5f; }
        if (lane + 64 < NN) {
            cxB=T[3*(lane+64)]; cyB=T[3*(lane+64)+1]; ccB=T[3*(lane+64)+2];
            vB_ = ccB > 0.5f;
        }
        unsigned long long mAv = __ballot(vA_);
        unsigned long long mBv = __ballot(vB_);
        int nA_ = __popcll(mAv);
        int K0  = nA_ + __popcll(mBv);
        unsigned long long below = (1ull << lane) - 1ull;
        if (vA_) { int q = __popcll(mAv & below);       tvx[q]=cxA; tvy[q]=cyA; tvc[q]=ccA; }
        if (vB_) { int q = nA_ + __popcll(mBv & below); tvx[q]=cxB; tvy[q]=cyB; tvc[q]=ccB; }
        if (lane == 0) Ksh = K0;
        claimArr[lane] = BIGCLAIM;
        if (lane + 64 <= MM) claimArr[lane + 64] = BIGCLAIM;
    }
    __syncthreads();                                  // barrier 1
    const int K = Ksh;
    if (K == 0) { if (tid == 0) ws[b] = 0.0; return; }

    float txA = (lane < K)      ? tvx[lane]      : 0.f;
    float tyA = (lane < K)      ? tvy[lane]      : 0.f;
    float txB = (lane + 64 < K) ? tvx[lane + 64] : 0.f;
    float tyB = (lane + 64 < K) ? tvy[lane + 64] : 0.f;

    // ---- cost build (waves split rows) + fused row argmin ----
    for (int c = wave; c < K; c += 2) {
        float tx = (c < 64) ? readlane_f(txA, c) : readlane_f(txB, c - 64);
        float ty = (c < 64) ? readlane_f(tyA, c) : readlane_f(tyB, c - 64);
        float dxA = __fsub_rn(pxA, tx), dyA = __fsub_rn(pyA, ty);
        float cA = __fsqrt_rn(__fadd_rn(__fmul_rn(dxA,dxA), __fmul_rn(dyA,dyA)));
        Tc[c*ST + lane] = cA;
        float cB = 1e30f;
        if (colBvalid) {
            float dxB = __fsub_rn(pxB, tx), dyB = __fsub_rn(pyB, ty);
            cB = __fsqrt_rn(__fadd_rn(__fmul_rn(dxB,dxB), __fmul_rn(dyB,dyB)));
            Tc[c*ST + lane + 64] = cB;
        }
        float m = wave_min_f32(fminf(cA, cB));
        unsigned long long eA = __ballot(cA == m);
        unsigned long long eB = __ballot(cB == m);
        int argc = eA ? ((int)__ffsll(eA) - 1) : ((int)__ffsll(eB) - 1 + 64);
        if (lane == 0) rmini[c] = argc;
    }
    __syncthreads();                                  // barrier 2
    if (wave == 1) return;

    // ================== wave 0 only from here ==================
    const float INF32 = __builtin_inff();
    const int jA = lane;                 // column 0..63 (0 = sentinel)
    const int jB = lane + 64;            // column 64..127; valid if <= 100
    const bool validB = (jB <= MM);
    const int idxA = (jA >= 1) ? (jA - 1) : 0;
    const int idxB = validB ? (jB - 1) : (MM - 1);

    // ---- greedy claim: min row index wins each argmin column ----
    int rA = lane + 1, rB = lane + 65;
    int argA = 0, argB = 0;
    if (lane < K)      { argA = rmini[lane] + 1;      atomicMin(&claimArr[argA], rA); }
    if (lane + 64 < K) { argB = rmini[lane + 64] + 1; atomicMin(&claimArr[argB], rB); }
    __threadfence_block();
    int pA = 0, pB = 0;
    if (jA >= 1) { int c0 = claimArr[jA]; pA = (c0 != BIGCLAIM) ? c0 : 0; }
    if (validB)  { int c0 = claimArr[jB]; pB = (c0 != BIGCLAIM) ? c0 : 0; }
    bool freeA = (lane < K)      && (claimArr[argA] != rA);
    bool freeB = (lane + 64 < K) && (claimArr[argB] != rB);
    unsigned long long fA = __ballot(freeA);
    unsigned long long fB = __ballot(freeB);

    float vvA = 0.f, vvB = 0.f;          // column potentials (f32)

    // ---- JV augmenting row reduction, 2 sweeps ----
    unsigned long long dijA = 0ull, dijB = 0ull;
    for (int sweep = 0; sweep < 2; ++sweep) {
        unsigned long long curA = fA, curB = fB;
        fA = 0ull; fB = 0ull;
        while (curA | curB) {
            int r;
            if (curA) { r = (int)__ffsll(curA);      curA &= curA - 1; }
            else      { r = (int)__ffsll(curB) + 64; curB &= curB - 1; }

            float cA = Tc[(r-1)*ST + idxA];
            float cB = Tc[(r-1)*ST + idxB];
            float rcA = (jA >= 1) ? (cA - vvA) : INF32;
            float rcB = validB ? (cB - vvB) : INF32;
            float m1 = wave_min_f32(fminf(rcA, rcB));
            unsigned long long eA = __ballot(rcA == m1);
            unsigned long long eB = __ballot(rcB == m1);
            int j1 = eA ? ((int)__ffsll(eA) - 1) : ((int)__ffsll(eB) - 1 + 64);

            float rcA2 = (jA == j1) ? INF32 : rcA;
            float rcB2 = (jB == j1) ? INF32 : rcB;
            float m2 = wave_min_f32(fminf(rcA2, rcB2));

            int holder = (j1 < 64) ? readlane_i(pA, j1) : readlane_i(pB, j1 & 63);

            if (m1 < m2) {
                float dv = m2 - m1;
                if (jA == j1) { vvA -= dv; pA = r; }
                if (validB && jB == j1) { vvB -= dv; pB = r; }
                if (holder != 0) {
                    if (sweep == 0) {
                        if (holder <= 64) fA |= 1ull << (holder - 1);
                        else              fB |= 1ull << (holder - 65);
                    } else {
                        if (holder <= 64) dijA |= 1ull << (holder - 1);
                        else              dijB |= 1ull << (holder - 65);
                    }
                }
            } else {                      // tie m1 == m2
                if (holder == 0) {
                    if (jA == j1) pA = r;
                    if (validB && jB == j1) pB = r;
                } else {
                    unsigned long long e2A = __ballot(rcA2 == m2);
                    unsigned long long e2B = __ballot(rcB2 == m2);
                    int j2 = e2A ? ((int)__ffsll(e2A) - 1)
                                 : ((int)__ffsll(e2B) - 1 + 64);
                    int h2 = (j2 < 64) ? readlane_i(pA, j2)
                                       : readlane_i(pB, j2 & 63);
                    if (h2 == 0) {
                        if (jA == j2) pA = r;
                        if (validB && jB == j2) pB = r;
                    } else {
                        if (sweep == 0) {
                            if (r <= 64) fA |= 1ull << (r - 1);
                            else         fB |= 1ull << (r - 65);
                        } else {
                            if (r <= 64) dijA |= 1ull << (r - 1);
                            else         dijB |= 1ull << (r - 65);
                        }
                    }
                }
            }
        }
    }

    // ---- f32 Dijkstra phases (absolute distances, implicit u, S0 = 0) ----
    while (dijA | dijB) {
        int r;
        if (dijA) { r = (int)__ffsll(dijA);      dijA &= dijA - 1; }
        else      { r = (int)__ffsll(dijB) + 64; dijB &= dijB - 1; }

        float minvA = INF32, minvB = INF32;
        int wayA = 0, wayB = 0;
        bool usedA = (lane == 0), usedB = false;
        float dpopA = 0.f, dpopB = 0.f;
        if (lane == 0) pA = r;           // p[0] = r (augment terminator)
        int j0 = 0, jfree = -1;
        float dstar = 0.f;

        float cA_f = Tc[(r-1)*ST + idxA];
        float cB_f = Tc[(r-1)*ST + idxB];
        float S = 0.f;                   // u0 arbitrary (uniform shift)

        for (int it = 0; it <= MM; ++it) {
            float candA = INF32, candB = INF32;
            if (jA >= 1 && !usedA) {
                float t = (cA_f - vvA) + S;
                if (t < minvA) { minvA = t; wayA = j0; }
                candA = minvA;
            }
            if (validB && !usedB) {
                float t = (cB_f - vvB) + S;
                if (t < minvB) { minvB = t; wayB = j0; }
                candB = minvB;
            }

            float delta = wave_min_f32(fminf(candA, candB));
            unsigned long long eA = __ballot(candA == delta);
            unsigned long long eB = __ballot(candB == delta);
            int j1 = eA ? ((int)__ffsll(eA) - 1) : ((int)__ffsll(eB) - 1 + 64);

            if (jA == j1) { usedA = true; dpopA = delta; }
            if (jB == j1) { usedB = true; dpopB = delta; }

            int pa = readlane_i(pA, j1 & 63);
            int pb = readlane_i(pB, j1 & 63);
            int pj1 = (j1 < 64) ? pa : pb;
            if (pj1 == 0) { jfree = j1; dstar = delta; break; }

            // prefetch next scan row; S = delta - u[pj1], u implicit
            float nxA = Tc[(pj1-1)*ST + idxA];
            float nxB = Tc[(pj1-1)*ST + idxB];
            float cjm = (j1 < 64) ? readlane_f(nxA, j1) : readlane_f(nxB, j1 & 63);
            float vjm = (j1 < 64) ? readlane_f(vvA, j1) : readlane_f(vvB, j1 & 63);
            S = (delta - cjm) + vjm;
            cA_f = nxA; cB_f = nxB;
            j0 = j1;
        }

        // phase-end potential update for scanned columns
        if (usedA && jA >= 1) vvA += dpopA - dstar;
        if (usedB)            vvB += dpopB - dstar;

        // augment along way[]
        int jc = jfree;
        for (int s = 0; s <= MM && jc > 0; ++s) {
            int wa = readlane_i(wayA, jc & 63);
            int wb = readlane_i(wayB, jc & 63);
            int w  = (jc < 64) ? wa : wb;
            int pa = readlane_i(pA, w & 63);
            int pb = readlane_i(pB, w & 63);
            int pw = (w < 64) ? pa : pb;
            if (jA == jc) pA = pw;
            if (jB == jc) pB = pw;
            jc = w;
        }
    }

    // ---- loss (f64, matches reference arithmetic) ----
    double se = 0.0, bce = 0.0;
    if (jA >= 1 && pA > 0) {
        int rr = jA - 1, c = pA - 1;
        float dx = __fsub_rn(px[rr], tvx[c]);
        float dy = __fsub_rn(py[rr], tvy[c]);
        se = (double)dx*(double)dx + (double)dy*(double)dy;
        double pcv = (double)pc[rr];
        pcv = fmin(fmax(pcv, 1e-12), 1.0 - 1e-12);
        double tc = (double)tvc[c];
        bce = -(tc * log(pcv) + (1.0 - tc) * log1p(-pcv));
    }
    if (validB && pB > 0) {
        int rr = jB - 1, c = pB - 1;
        float dx = __fsub_rn(px[rr], tvx[c]);
        float dy = __fsub_rn(py[rr], tvy[c]);
        se += (double)dx*(double)dx + (double)dy*(double)dy;
        double pcv = (double)pc[rr];
        pcv = fmin(fmax(pcv, 1e-12), 1.0 - 1e-12);
        double tc = (double)tvc[c];
        bce += -(tc * log(pcv) + (1.0 - tc) * log1p(-pcv));
    }
    for (int m = 1; m < 64; m <<= 1) {
        se  += __shfl_xor(se,  m, 64);
        bce += __shfl_xor(bce, m, 64);
    }
    if (lane == 0) ws[b] = se / (2.0 * (double)K) + bce / (double)K;
}

__global__ __launch_bounds__(64) void final_reduce(const double* __restrict__ ws,
                                                   float* __restrict__ out) {
    double v = ws[threadIdx.x];   // BATCH == 64 == one wave
    for (int m = 1; m < 64; m <<= 1) v += __shfl_xor(v, m, 64);
    if (threadIdx.x == 0) out[0] = (float)(v / (double)BATCH);
}

extern "C" void kernel_launch(void* const* d_in, const int* in_sizes, int n_in,
                              void* d_out, int out_size, void* d_ws, size_t ws_size,
                              hipStream_t stream) {
    const float* pred   = (const float*)d_in[0];
    const float* target = (const float*)d_in[1];
    double* ws = (double*)d_ws;
    float* out = (float*)d_out;
    hungarian_loss_kernel<<<dim3(BATCH), dim3(128), 0, stream>>>(pred, target, ws);
    final_reduce<<<dim3(1), dim3(64), 0, stream>>>(ws, out);
}